// Round 2
// baseline (465.188 us; speedup 1.0000x reference)
//
#include <hip/hip_runtime.h>

typedef unsigned short ushort_t;
typedef __attribute__((ext_vector_type(8))) short short8;
typedef __attribute__((ext_vector_type(4))) float float4v;
typedef __attribute__((ext_vector_type(4))) ushort_t ushort4v;

#define B_ROWS 8192
#define HDIM   1024
#define GLD    5120   // G cols: [hat(c) | t6(hat_raw) | r | z | xh]

__device__ __forceinline__ float bf2f(ushort_t u) {
    return __uint_as_float(((unsigned)u) << 16);
}
__device__ __forceinline__ ushort_t f2bf(float f) {
    unsigned u = __float_as_uint(f);
    u += 0x7FFFu + ((u >> 16) & 1u);   // round-to-nearest-even
    return (ushort_t)(u >> 16);
}

// ---- pack fp32 -> bf16 scratch ---------------------------------------------

// Abf[b, 0:1024] = x[b], Abf[b, 1024:2048] = hidden[b]   ([8192, 2048])
__global__ __launch_bounds__(256) void pack_A(
    const float* __restrict__ x, const float* __restrict__ h,
    ushort_t* __restrict__ A)
{
    size_t i4 = ((size_t)blockIdx.x * 256 + threadIdx.x) * 4;
    int c = (int)(i4 & 2047);
    size_t b = i4 >> 11;
    const float* src = (c < 1024) ? (x + b * 1024 + c) : (h + b * 1024 + (c - 1024));
    float4v v = *(const float4v*)src;
    ushort4v o;
#pragma unroll
    for (int t = 0; t < 4; ++t) o[t] = f2bf(v[t]);
    *(ushort4v*)(A + i4) = o;
}

// W [5120, 2048]: rows 0-1023 wc | 1024-2047 what | 2048-3071 [wxr|whr]
//                 3072-4095 [wxz|whz] | 4096-5119 [wxh|zeros]
__global__ __launch_bounds__(256) void pack_W(
    const float* __restrict__ wc, const float* __restrict__ what,
    const float* __restrict__ wxr, const float* __restrict__ whr,
    const float* __restrict__ wxz, const float* __restrict__ whz,
    const float* __restrict__ wxh, ushort_t* __restrict__ W)
{
    size_t i4 = ((size_t)blockIdx.x * 256 + threadIdx.x) * 4;
    int j = (int)(i4 >> 11);
    int k = (int)(i4 & 2047);
    int r = j >> 10, jr = j & 1023;
    float4v v;
    if (r == 0) {
        v = *(const float4v*)(wc + (size_t)j * 2048 + k);
    } else if (r == 1) {
        v = *(const float4v*)(what + (size_t)jr * 2048 + k);
    } else if (r == 4) {
        if (k < 1024) v = *(const float4v*)(wxh + (size_t)jr * 1024 + k);
        else          v = (float4v){0.f, 0.f, 0.f, 0.f};
    } else {
        const float* p0 = (r == 2) ? wxr : wxz;
        const float* p1 = (r == 2) ? whr : whz;
        const float* p = (k < 1024) ? (p0 + (size_t)jr * 1024 + k)
                                    : (p1 + (size_t)jr * 1024 + (k - 1024));
        v = *(const float4v*)p;
    }
    ushort4v o;
#pragma unroll
    for (int t = 0; t < 4; ++t) o[t] = f2bf(v[t]);
    *(ushort4v*)(W + i4) = o;
}

__global__ __launch_bounds__(256) void conv_bf(
    const float* __restrict__ src, ushort_t* __restrict__ dst)
{
    size_t i4 = ((size_t)blockIdx.x * 256 + threadIdx.x) * 4;
    float4v v = *(const float4v*)(src + i4);
    ushort4v o;
#pragma unroll
    for (int t = 0; t < 4; ++t) o[t] = f2bf(v[t]);
    *(ushort4v*)(dst + i4) = o;
}

// ---- bf16 GEMM, C = A @ B^T (m97 structure) --------------------------------
// A [M,K] lda, B [N,K] ldb, C [M,N-window] ldc, all bf16. 128x128 tile, BK=32.
__global__ __launch_bounds__(256) void gemm_bt(
    const ushort_t* __restrict__ A, const ushort_t* __restrict__ B,
    ushort_t* __restrict__ C, int lda, int ldb, int ldc, int K)
{
    const int bn0 = blockIdx.x * 128;
    const int bm0 = blockIdx.y * 128;

    __shared__ ushort_t As[128 * 32];
    __shared__ ushort_t Bs[128 * 32];

    const int t = threadIdx.x;
    const int wave = t >> 6, lane = t & 63;
    const int wr = wave >> 1, wcq = wave & 1;    // wave's 64x64 quadrant
    const int q = lane >> 4, r16 = lane & 15;
    const int lrow = lane >> 2;                  // 0..15
    const int lcol = (lane & 3) * 8;             // 0,8,16,24

    float4v acc[4][4];
#pragma unroll
    for (int i = 0; i < 4; ++i)
#pragma unroll
        for (int j = 0; j < 4; ++j)
            acc[i][j] = {0.f, 0.f, 0.f, 0.f};

    for (int k0 = 0; k0 < K; k0 += 32) {
        if (wave < 2) {
#pragma unroll
            for (int j = 0; j < 4; ++j) {
                int c = wave * 4 + j;
                const ushort_t* gp = A + (size_t)(bm0 + c * 16 + lrow) * lda + k0 + lcol;
                __builtin_amdgcn_global_load_lds(
                    (const __attribute__((address_space(1))) void*)gp,
                    (__attribute__((address_space(3))) void*)(As + c * 512),
                    16, 0, 0);
            }
        } else {
#pragma unroll
            for (int j = 0; j < 4; ++j) {
                int c = (wave - 2) * 4 + j;
                const ushort_t* gp = B + (size_t)(bn0 + c * 16 + lrow) * ldb + k0 + lcol;
                __builtin_amdgcn_global_load_lds(
                    (const __attribute__((address_space(1))) void*)gp,
                    (__attribute__((address_space(3))) void*)(Bs + c * 512),
                    16, 0, 0);
            }
        }
        __syncthreads();

        short8 af[4], bf[4];
#pragma unroll
        for (int mi = 0; mi < 4; ++mi)
            af[mi] = *(const short8*)&As[(wr * 64 + mi * 16 + r16) * 32 + q * 8];
#pragma unroll
        for (int ni = 0; ni < 4; ++ni)
            bf[ni] = *(const short8*)&Bs[(wcq * 64 + ni * 16 + r16) * 32 + q * 8];
#pragma unroll
        for (int mi = 0; mi < 4; ++mi)
#pragma unroll
            for (int ni = 0; ni < 4; ++ni)
                acc[mi][ni] = __builtin_amdgcn_mfma_f32_16x16x32_bf16(
                    af[mi], bf[ni], acc[mi][ni], 0, 0, 0);
        __syncthreads();
    }

    // C/D layout: col = lane&15, row = (lane>>4)*4 + reg  [m89/m91]
#pragma unroll
    for (int mi = 0; mi < 4; ++mi)
#pragma unroll
        for (int ni = 0; ni < 4; ++ni)
#pragma unroll
            for (int reg = 0; reg < 4; ++reg) {
                int row = bm0 + wr * 64 + mi * 16 + q * 4 + reg;
                int col = bn0 + wcq * 64 + ni * 16 + r16;
                C[(size_t)row * ldc + col] = f2bf(acc[mi][ni][reg]);
            }
}

// ---- elementwise -----------------------------------------------------------

// rh = bf16( sigmoid(G_r + bias_r) * hidden )
__global__ __launch_bounds__(256) void rh_kernel(
    const ushort_t* __restrict__ G, const float* __restrict__ bias_r,
    const float* __restrict__ hidden, ushort_t* __restrict__ rh)
{
    size_t i = (size_t)blockIdx.x * 256 + threadIdx.x;
    size_t b = i >> 10;
    int h = (int)(i & 1023);
    float g = bf2f(G[b * GLD + 2048 + h]) + bias_r[h];
    float r = 1.0f / (1.0f + __expf(-g));
    rh[i] = f2bf(r * hidden[i]);
}

// In-place: G[:,0:1024] = softmax(c + bias_c) * relu(hat_raw + bias_hat)
__global__ __launch_bounds__(256) void softmax_hat(
    ushort_t* __restrict__ G, const float* __restrict__ bias_c,
    const float* __restrict__ bias_hat)
{
    ushort_t* row = G + (size_t)blockIdx.x * GLD;
    const int t = threadIdx.x;
    float cv[4];
    float mx = -1e30f;
#pragma unroll
    for (int i = 0; i < 4; ++i) {
        int h = t * 4 + i;
        cv[i] = bf2f(row[h]) + bias_c[h];
        mx = fmaxf(mx, cv[i]);
    }
    __shared__ float red[256];
    red[t] = mx;
    __syncthreads();
    for (int s = 128; s > 0; s >>= 1) {
        if (t < s) red[t] = fmaxf(red[t], red[t + s]);
        __syncthreads();
    }
    mx = red[0];
    __syncthreads();
    float sum = 0.f;
#pragma unroll
    for (int i = 0; i < 4; ++i) { cv[i] = __expf(cv[i] - mx); sum += cv[i]; }
    red[t] = sum;
    __syncthreads();
    for (int s = 128; s > 0; s >>= 1) {
        if (t < s) red[t] += red[t + s];
        __syncthreads();
    }
    float inv = 1.0f / red[0];
#pragma unroll
    for (int i = 0; i < 4; ++i) {
        int h = t * 4 + i;
        float hr = bf2f(row[1024 + h]) + bias_hat[h];
        row[h] = f2bf(cv[i] * inv * fmaxf(hr, 0.f));
    }
}

// h_t = (1-z)*tanh(xh + bias_h + t6) + z*hidden + hat   (fp32 out)
__global__ __launch_bounds__(256) void final_kernel(
    const ushort_t* __restrict__ G, const float* __restrict__ bias_z,
    const float* __restrict__ bias_h, const float* __restrict__ hidden,
    float* __restrict__ out)
{
    size_t i = (size_t)blockIdx.x * 256 + threadIdx.x;
    size_t b = i >> 10;
    int h = (int)(i & 1023);
    const ushort_t* row = G + b * GLD;
    float z = 1.0f / (1.0f + __expf(-(bf2f(row[3072 + h]) + bias_z[h])));
    float targ = bf2f(row[4096 + h]) + bias_h[h] + bf2f(row[1024 + h]);
    float th = 1.0f - 2.0f / (__expf(2.0f * targ) + 1.0f);   // tanh, overflow-safe
    out[i] = (1.0f - z) * th + z * hidden[i] + bf2f(row[h]);
}

// ---- launch ----------------------------------------------------------------

extern "C" void kernel_launch(void* const* d_in, const int* in_sizes, int n_in,
                              void* d_out, int out_size, void* d_ws, size_t ws_size,
                              hipStream_t stream)
{
    const float* x        = (const float*)d_in[0];
    const float* hidden   = (const float*)d_in[1];
    const float* wxr      = (const float*)d_in[2];
    const float* whr      = (const float*)d_in[3];
    const float* bias_r   = (const float*)d_in[4];
    const float* wxz      = (const float*)d_in[5];
    const float* whz      = (const float*)d_in[6];
    const float* bias_z   = (const float*)d_in[7];
    const float* wxh      = (const float*)d_in[8];
    const float* whh      = (const float*)d_in[9];
    const float* bias_h   = (const float*)d_in[10];
    const float* wc       = (const float*)d_in[11];
    const float* bias_c   = (const float*)d_in[12];
    const float* what     = (const float*)d_in[13];
    const float* bias_hat = (const float*)d_in[14];
    float* out = (float*)d_out;

    char* ws = (char*)d_ws;
    ushort_t* G     = (ushort_t*)(ws);                    // [8192,5120] bf16, 80 MiB
    ushort_t* Abf   = (ushort_t*)(ws + 83886080);         // [8192,2048] bf16, 32 MiB
    ushort_t* Wbf   = (ushort_t*)(ws + 117440512);        // [5120,2048] bf16, 20 MiB
    ushort_t* Whhbf = (ushort_t*)(ws + 138412032);        // [1024,1024] bf16,  2 MiB
    ushort_t* rhbf  = (ushort_t*)(ws + 140509184);        // [8192,1024] bf16, 16 MiB

    pack_A<<<(B_ROWS * 2048) / (256 * 4), 256, 0, stream>>>(x, hidden, Abf);
    pack_W<<<(5120 * 2048) / (256 * 4), 256, 0, stream>>>(
        wc, what, wxr, whr, wxz, whz, wxh, Wbf);
    conv_bf<<<(1024 * 1024) / (256 * 4), 256, 0, stream>>>(whh, Whhbf);

    // GEMM1: G = Abf @ Wbf^T   (M=8192, N=5120, K=2048)
    gemm_bt<<<dim3(40, 64), 256, 0, stream>>>(Abf, Wbf, G, 2048, 2048, GLD, 2048);

    rh_kernel<<<(B_ROWS * HDIM) / 256, 256, 0, stream>>>(G, bias_r, hidden, rhbf);
    softmax_hat<<<B_ROWS, 256, 0, stream>>>(G, bias_c, bias_hat);

    // GEMM2: G[:,1024:2048) = rhbf @ Whh^T   (M=8192, N=1024, K=1024)
    gemm_bt<<<dim3(8, 64), 256, 0, stream>>>(rhbf, Whhbf, G + 1024, 1024, 1024, GLD, 1024);

    final_kernel<<<(B_ROWS * HDIM) / 256, 256, 0, stream>>>(
        G, bias_z, bias_h, hidden, out);
}

// Round 3
// 419.533 us; speedup vs baseline: 1.1088x; 1.1088x over previous
//
#include <hip/hip_runtime.h>

typedef unsigned short ushort_t;
typedef __attribute__((ext_vector_type(8))) short short8;
typedef __attribute__((ext_vector_type(4))) float float4v;
typedef __attribute__((ext_vector_type(4))) ushort_t ushort4v;

#define B_ROWS 8192
#define HDIM   1024
#define GLD    5120   // G cols: [hat(c) | hat_raw | r | z | xh]

__device__ __forceinline__ float bf2f(ushort_t u) {
    return __uint_as_float(((unsigned)u) << 16);
}
__device__ __forceinline__ ushort_t f2bf(float f) {
    unsigned u = __float_as_uint(f);
    u += 0x7FFFu + ((u >> 16) & 1u);   // round-to-nearest-even
    return (ushort_t)(u >> 16);
}

// ---- one pack kernel for A, W, Whh ----------------------------------------
// grid.x = 16384 (A: 8192x2048) + 10240 (W: 5120x2048) + 1024 (Whh: 1024x1024)
__global__ __launch_bounds__(256) void pack_all(
    const float* __restrict__ x, const float* __restrict__ h,
    const float* __restrict__ wc, const float* __restrict__ what,
    const float* __restrict__ wxr, const float* __restrict__ whr,
    const float* __restrict__ wxz, const float* __restrict__ whz,
    const float* __restrict__ wxh, const float* __restrict__ whh,
    ushort_t* __restrict__ A, ushort_t* __restrict__ W,
    ushort_t* __restrict__ Whh)
{
    const int bid = blockIdx.x;
    float4v v;
    ushort_t* dst;
    size_t i4;
    if (bid < 16384) {                       // ---- A = [x | hidden]
        i4 = ((size_t)bid * 256 + threadIdx.x) * 4;
        int c = (int)(i4 & 2047);
        size_t b = i4 >> 11;
        const float* src = (c < 1024) ? (x + b * 1024 + c)
                                      : (h + b * 1024 + (c - 1024));
        v = *(const float4v*)src;
        dst = A + i4;
    } else if (bid < 26624) {                // ---- W rows: wc|what|[xr|hr]|[xz|hz]|[xh|junk]
        i4 = ((size_t)(bid - 16384) * 256 + threadIdx.x) * 4;
        int j = (int)(i4 >> 11);
        int k = (int)(i4 & 2047);
        int r = j >> 10, jr = j & 1023;
        if (r == 0) {
            v = *(const float4v*)(wc + (size_t)j * 2048 + k);
        } else if (r == 1) {
            v = *(const float4v*)(what + (size_t)jr * 2048 + k);
        } else if (r == 4) {
            // K=1024 for this region in the GEMM; k>=1024 never read
            v = (k < 1024) ? *(const float4v*)(wxh + (size_t)jr * 1024 + k)
                           : (float4v){0.f, 0.f, 0.f, 0.f};
        } else {
            const float* p0 = (r == 2) ? wxr : wxz;
            const float* p1 = (r == 2) ? whr : whz;
            const float* p = (k < 1024) ? (p0 + (size_t)jr * 1024 + k)
                                        : (p1 + (size_t)jr * 1024 + (k - 1024));
            v = *(const float4v*)p;
        }
        dst = W + i4;
    } else {                                 // ---- Whh
        i4 = ((size_t)(bid - 26624) * 256 + threadIdx.x) * 4;
        v = *(const float4v*)(whh + i4);
        dst = Whh + i4;
    }
    ushort4v o;
#pragma unroll
    for (int t = 0; t < 4; ++t) o[t] = f2bf(v[t]);
    *(ushort4v*)dst = o;
}

// ---- GEMM1: G = A @ W^T, bf16 out, variable K per n-region -----------------
// m97 structure: 128x128 tile, BK=32, 4 waves of 64x64, global_load_lds w=16.
__global__ __launch_bounds__(256) void gemm1(
    const ushort_t* __restrict__ A, const ushort_t* __restrict__ B,
    ushort_t* __restrict__ C)
{
    const int bn0 = blockIdx.x * 128;
    const int bm0 = blockIdx.y * 128;
    const int K = (bn0 >= 4096) ? 1024 : 2048;   // xh region has K=1024

    __shared__ ushort_t As[128 * 32];
    __shared__ ushort_t Bs[128 * 32];

    const int t = threadIdx.x;
    const int wave = t >> 6, lane = t & 63;
    const int wr = wave >> 1, wcq = wave & 1;
    const int q = lane >> 4, r16 = lane & 15;
    const int lrow = lane >> 2;
    const int lcol = (lane & 3) * 8;

    float4v acc[4][4];
#pragma unroll
    for (int i = 0; i < 4; ++i)
#pragma unroll
        for (int j = 0; j < 4; ++j)
            acc[i][j] = {0.f, 0.f, 0.f, 0.f};

    for (int k0 = 0; k0 < K; k0 += 32) {
        if (wave < 2) {
#pragma unroll
            for (int j = 0; j < 4; ++j) {
                int c = wave * 4 + j;
                const ushort_t* gp = A + (size_t)(bm0 + c * 16 + lrow) * 2048 + k0 + lcol;
                __builtin_amdgcn_global_load_lds(
                    (const __attribute__((address_space(1))) void*)gp,
                    (__attribute__((address_space(3))) void*)(As + c * 512),
                    16, 0, 0);
            }
        } else {
#pragma unroll
            for (int j = 0; j < 4; ++j) {
                int c = (wave - 2) * 4 + j;
                const ushort_t* gp = B + (size_t)(bn0 + c * 16 + lrow) * 2048 + k0 + lcol;
                __builtin_amdgcn_global_load_lds(
                    (const __attribute__((address_space(1))) void*)gp,
                    (__attribute__((address_space(3))) void*)(Bs + c * 512),
                    16, 0, 0);
            }
        }
        __syncthreads();

        short8 af[4], bf[4];
#pragma unroll
        for (int mi = 0; mi < 4; ++mi)
            af[mi] = *(const short8*)&As[(wr * 64 + mi * 16 + r16) * 32 + q * 8];
#pragma unroll
        for (int ni = 0; ni < 4; ++ni)
            bf[ni] = *(const short8*)&Bs[(wcq * 64 + ni * 16 + r16) * 32 + q * 8];
#pragma unroll
        for (int mi = 0; mi < 4; ++mi)
#pragma unroll
            for (int ni = 0; ni < 4; ++ni)
                acc[mi][ni] = __builtin_amdgcn_mfma_f32_16x16x32_bf16(
                    af[mi], bf[ni], acc[mi][ni], 0, 0, 0);
        __syncthreads();
    }

    // C/D layout: col = lane&15, row = (lane>>4)*4 + reg  [m89/m91]
#pragma unroll
    for (int mi = 0; mi < 4; ++mi)
#pragma unroll
        for (int ni = 0; ni < 4; ++ni)
#pragma unroll
            for (int reg = 0; reg < 4; ++reg) {
                int row = bm0 + wr * 64 + mi * 16 + q * 4 + reg;
                int col = bn0 + wcq * 64 + ni * 16 + r16;
                C[(size_t)row * GLD + col] = f2bf(acc[mi][ni][reg]);
            }
}

// ---- fused row pass: softmax*relu (hat) + rh, wave-per-row, no syncs -------
// G[:,0:1024) <- softmax(c+bias_c)*relu(hat_raw+bias_hat);  rh <- sigmoid(r+bias_r)*hidden
__global__ __launch_bounds__(256) void row_pass(
    ushort_t* __restrict__ G, const float* __restrict__ bias_c,
    const float* __restrict__ bias_hat, const float* __restrict__ bias_r,
    const float* __restrict__ hidden, ushort_t* __restrict__ rh)
{
    const int wave = threadIdx.x >> 6, lane = threadIdx.x & 63;
    const size_t row = (size_t)blockIdx.x * 4 + wave;
    ushort_t* g = G + row * GLD;
    const int c0 = lane * 16;                 // 16 contiguous cols per lane

    // softmax over c
    float cv[16];
    {
        short8 a = *(const short8*)(g + c0);
        short8 b = *(const short8*)(g + c0 + 8);
#pragma unroll
        for (int i = 0; i < 8; ++i) {
            cv[i]     = bf2f((ushort_t)a[i]) + bias_c[c0 + i];
            cv[8 + i] = bf2f((ushort_t)b[i]) + bias_c[c0 + 8 + i];
        }
    }
    float mx = cv[0];
#pragma unroll
    for (int i = 1; i < 16; ++i) mx = fmaxf(mx, cv[i]);
#pragma unroll
    for (int m = 1; m < 64; m <<= 1) mx = fmaxf(mx, __shfl_xor(mx, m));
    float sum = 0.f;
#pragma unroll
    for (int i = 0; i < 16; ++i) { cv[i] = __expf(cv[i] - mx); sum += cv[i]; }
#pragma unroll
    for (int m = 1; m < 64; m <<= 1) sum += __shfl_xor(sum, m);
    const float inv = 1.0f / sum;

    // hat = p * relu(hat_raw + bias_hat)  -> overwrite c cols
    {
        short8 a = *(const short8*)(g + 1024 + c0);
        short8 b = *(const short8*)(g + 1024 + c0 + 8);
        short8 oa, ob;
#pragma unroll
        for (int i = 0; i < 8; ++i) {
            float ha = bf2f((ushort_t)a[i]) + bias_hat[c0 + i];
            float hb = bf2f((ushort_t)b[i]) + bias_hat[c0 + 8 + i];
            oa[i] = (short)f2bf(cv[i] * inv * fmaxf(ha, 0.f));
            ob[i] = (short)f2bf(cv[8 + i] * inv * fmaxf(hb, 0.f));
        }
        *(short8*)(g + c0) = oa;
        *(short8*)(g + c0 + 8) = ob;
    }

    // rh = sigmoid(r + bias_r) * hidden
    {
        short8 a = *(const short8*)(g + 2048 + c0);
        short8 b = *(const short8*)(g + 2048 + c0 + 8);
        const float* hp = hidden + row * 1024 + c0;
        short8 oa, ob;
#pragma unroll
        for (int i = 0; i < 8; ++i) {
            float ra = 1.0f / (1.0f + __expf(-(bf2f((ushort_t)a[i]) + bias_r[c0 + i])));
            float rb = 1.0f / (1.0f + __expf(-(bf2f((ushort_t)b[i]) + bias_r[c0 + 8 + i])));
            oa[i] = (short)f2bf(ra * hp[i]);
            ob[i] = (short)f2bf(rb * hp[8 + i]);
        }
        ushort_t* rp = rh + row * 1024 + c0;
        *(short8*)rp = oa;
        *(short8*)(rp + 8) = ob;
    }
}

// ---- GEMM2 with fused final epilogue ---------------------------------------
// t6 = rh @ Whh^T (tile in regs), then
// out = (1-z)*tanh(xh + bias_h + t6) + z*hidden + hat
__global__ __launch_bounds__(256) void gemm2_final(
    const ushort_t* __restrict__ A, const ushort_t* __restrict__ B,
    const ushort_t* __restrict__ G, const float* __restrict__ bias_z,
    const float* __restrict__ bias_h, const float* __restrict__ hidden,
    float* __restrict__ out)
{
    const int bn0 = blockIdx.x * 128;
    const int bm0 = blockIdx.y * 128;

    __shared__ ushort_t As[128 * 32];
    __shared__ ushort_t Bs[128 * 32];

    const int t = threadIdx.x;
    const int wave = t >> 6, lane = t & 63;
    const int wr = wave >> 1, wcq = wave & 1;
    const int q = lane >> 4, r16 = lane & 15;
    const int lrow = lane >> 2;
    const int lcol = (lane & 3) * 8;

    float4v acc[4][4];
#pragma unroll
    for (int i = 0; i < 4; ++i)
#pragma unroll
        for (int j = 0; j < 4; ++j)
            acc[i][j] = {0.f, 0.f, 0.f, 0.f};

    for (int k0 = 0; k0 < 1024; k0 += 32) {
        if (wave < 2) {
#pragma unroll
            for (int j = 0; j < 4; ++j) {
                int c = wave * 4 + j;
                const ushort_t* gp = A + (size_t)(bm0 + c * 16 + lrow) * 1024 + k0 + lcol;
                __builtin_amdgcn_global_load_lds(
                    (const __attribute__((address_space(1))) void*)gp,
                    (__attribute__((address_space(3))) void*)(As + c * 512),
                    16, 0, 0);
            }
        } else {
#pragma unroll
            for (int j = 0; j < 4; ++j) {
                int c = (wave - 2) * 4 + j;
                const ushort_t* gp = B + (size_t)(bn0 + c * 16 + lrow) * 1024 + k0 + lcol;
                __builtin_amdgcn_global_load_lds(
                    (const __attribute__((address_space(1))) void*)gp,
                    (__attribute__((address_space(3))) void*)(Bs + c * 512),
                    16, 0, 0);
            }
        }
        __syncthreads();

        short8 af[4], bf[4];
#pragma unroll
        for (int mi = 0; mi < 4; ++mi)
            af[mi] = *(const short8*)&As[(wr * 64 + mi * 16 + r16) * 32 + q * 8];
#pragma unroll
        for (int ni = 0; ni < 4; ++ni)
            bf[ni] = *(const short8*)&Bs[(wcq * 64 + ni * 16 + r16) * 32 + q * 8];
#pragma unroll
        for (int mi = 0; mi < 4; ++mi)
#pragma unroll
            for (int ni = 0; ni < 4; ++ni)
                acc[mi][ni] = __builtin_amdgcn_mfma_f32_16x16x32_bf16(
                    af[mi], bf[ni], acc[mi][ni], 0, 0, 0);
        __syncthreads();
    }

#pragma unroll
    for (int mi = 0; mi < 4; ++mi)
#pragma unroll
        for (int ni = 0; ni < 4; ++ni) {
            const int col = bn0 + wcq * 64 + ni * 16 + r16;
            const float bz = bias_z[col];
            const float bh = bias_h[col];
#pragma unroll
            for (int reg = 0; reg < 4; ++reg) {
                const int row = bm0 + wr * 64 + mi * 16 + q * 4 + reg;
                const ushort_t* grow = G + (size_t)row * GLD;
                float z = 1.0f / (1.0f + __expf(-(bf2f(grow[3072 + col]) + bz)));
                float targ = bf2f(grow[4096 + col]) + bh + acc[mi][ni][reg];
                float th = 1.0f - 2.0f / (__expf(2.0f * targ) + 1.0f);
                out[(size_t)row * 1024 + col] =
                    (1.0f - z) * th + z * hidden[(size_t)row * 1024 + col]
                    + bf2f(grow[col]);
            }
        }
}

// ---- launch ----------------------------------------------------------------

extern "C" void kernel_launch(void* const* d_in, const int* in_sizes, int n_in,
                              void* d_out, int out_size, void* d_ws, size_t ws_size,
                              hipStream_t stream)
{
    const float* x        = (const float*)d_in[0];
    const float* hidden   = (const float*)d_in[1];
    const float* wxr      = (const float*)d_in[2];
    const float* whr      = (const float*)d_in[3];
    const float* bias_r   = (const float*)d_in[4];
    const float* wxz      = (const float*)d_in[5];
    const float* whz      = (const float*)d_in[6];
    const float* bias_z   = (const float*)d_in[7];
    const float* wxh      = (const float*)d_in[8];
    const float* whh      = (const float*)d_in[9];
    const float* bias_h   = (const float*)d_in[10];
    const float* wc       = (const float*)d_in[11];
    const float* bias_c   = (const float*)d_in[12];
    const float* what     = (const float*)d_in[13];
    const float* bias_hat = (const float*)d_in[14];
    float* out = (float*)d_out;

    char* ws = (char*)d_ws;
    ushort_t* G     = (ushort_t*)(ws);                    // [8192,5120] bf16, 80 MiB
    ushort_t* Abf   = (ushort_t*)(ws + 83886080);         // [8192,2048] bf16, 32 MiB
    ushort_t* Wbf   = (ushort_t*)(ws + 117440512);        // [5120,2048] bf16, 20 MiB
    ushort_t* Whhbf = (ushort_t*)(ws + 138412032);        // [1024,1024] bf16,  2 MiB
    ushort_t* rhbf  = (ushort_t*)(ws + 140509184);        // [8192,1024] bf16, 16 MiB

    pack_all<<<27648, 256, 0, stream>>>(x, hidden, wc, what, wxr, whr, wxz, whz,
                                        wxh, whh, Abf, Wbf, Whhbf);

    // GEMM1: G = Abf @ Wbf^T   (M=8192, N=5120, K=2048; xh region K=1024)
    gemm1<<<dim3(40, 64), 256, 0, stream>>>(Abf, Wbf, G);

    // fused softmax/hat + rh (wave per row)
    row_pass<<<B_ROWS / 4, 256, 0, stream>>>(G, bias_c, bias_hat, bias_r, hidden, rhbf);

    // GEMM2 + final epilogue -> out
    gemm2_final<<<dim3(8, 64), 256, 0, stream>>>(rhbf, Whhbf, G, bias_z, bias_h,
                                                 hidden, out);
}